// Round 17
// baseline (451.584 us; speedup 1.0000x reference)
//
#include <hip/hip_runtime.h>
#include <hip/hip_cooperative_groups.h>

namespace cg = cooperative_groups;

#define N_NODES 4096
#define N_EDGES 65536
#define MID 32
#define BN_EPS 1e-5f

// ---- workspace layout ----
// float offsets:
#define WS_RSUM    0
#define WS_RSUMSQ  1
#define WS_ALPHA1  272
#define WS_BETA1   400
#define WS_A2      528
#define WS_S2      656
#define WS_GRAM    5120   // floats 5120..9215
#define WS_SUMY    9216   // floats 9216..9343
#define WS_W2T     17664  // [4][32][32] fp32 (p,c,k)
#define WS_MSG_F   262144 // [E][64] fp32 messages
#define WS_U00     4456448 // [N][16]
#define WS_U01     4521984 // [N][16]
#define WS_V10     4587520 // [N][3q][16m]
#define WS_W11     4784128 // [N][9][16m]
// int offsets:
#define WS_DEG_I   1024
#define WS_CUR_I   9344
#define WS_OFFS_I  13440
#define WS_ELIST_I 65536
// byte offsets (weight images):
#define WSB_WA     524288 // 512 cols x 32 bf16 (32 KB)
#define WSB_WB     557056 // 256 cols (16 KB)
#define WSB_WC     573440 // 768 cols f-major (48 KB)

typedef short bf16x8 __attribute__((ext_vector_type(8)));
typedef float f32x4  __attribute__((ext_vector_type(4)));

__device__ __forceinline__ unsigned short f2bf(float x) {
    unsigned u = __float_as_uint(x);
    u += 0x7fffu + ((u >> 16) & 1u);   // RNE
    return (unsigned short)(u >> 16);
}

// y2 channels [c0,c0+16) of (pair p, edge el) -> bf16 to LDS at dst + el*64 + c0*2
__device__ __forceinline__ void y2_lds16(int p, int el, int c0, float rv,
                                         const float* __restrict__ wsf,
                                         const float* __restrict__ rb2, char* dst) {
    float y1[MID];
#pragma unroll
    for (int k = 0; k < MID; ++k)
        y1[k] = fmaxf(0.f, wsf[WS_ALPHA1 + p * 32 + k] * rv + wsf[WS_BETA1 + p * 32 + k]);
    unsigned short h[16];
#pragma unroll
    for (int cc = 0; cc < 16; ++cc) {
        int c = c0 + cc;
        float x = rb2[p * 32 + c];
#pragma unroll
        for (int k = 0; k < MID; ++k) x += y1[k] * wsf[WS_W2T + p * 1024 + c * 32 + k];
        h[cc] = f2bf(fmaxf(0.f, wsf[WS_A2 + p * 32 + c] * x + wsf[WS_S2 + p * 32 + c]));
    }
#pragma unroll
    for (int q = 0; q < 2; ++q) {
        int4 pk;
        pk.x = (int)h[q * 8 + 0] | ((int)h[q * 8 + 1] << 16);
        pk.y = (int)h[q * 8 + 2] | ((int)h[q * 8 + 3] << 16);
        pk.z = (int)h[q * 8 + 4] | ((int)h[q * 8 + 5] << 16);
        pk.w = (int)h[q * 8 + 6] | ((int)h[q * 8 + 7] << 16);
        *(int4*)(dst + el * 64 + c0 * 2 + q * 16) = pk;
    }
}

// ================= THE cooperative mega-kernel =================
// grid 256 x 512 (1 block/CU, co-resident), dyn LDS 64 KB, 128-VGPR regime.
__global__ void __launch_bounds__(512, 2) k_all(
        const float* __restrict__ rw2,
        const float* __restrict__ w300, const float* __restrict__ w301,
        const float* __restrict__ w310, const float* __restrict__ w311,
        const float* __restrict__ bw300, const float* __restrict__ bw301,
        const float* __restrict__ bw310, const float* __restrict__ bw311,
        const float* __restrict__ r, const int* __restrict__ edst,
        const int* __restrict__ esrc,
        const float* __restrict__ h0, const float* __restrict__ h1,
        const float* __restrict__ b00, const float* __restrict__ b01,
        const float* __restrict__ b10, const float* __restrict__ b11,
        const float* __restrict__ rw1, const float* __restrict__ rg1,
        const float* __restrict__ rbe1, const float* __restrict__ rb2,
        const float* __restrict__ rg2, const float* __restrict__ rbe2,
        const float* __restrict__ Wself0, const float* __restrict__ Wself1,
        float* __restrict__ wsf, float* __restrict__ msg,
        float* __restrict__ out) {
    extern __shared__ char smem[];
    cg::grid_group grid = cg::this_grid();
    int tid = threadIdx.x;
    int blk = blockIdx.x;
    int wv = tid >> 6, lane = tid & 63;
    int quad = lane >> 4, lq = lane & 15;
    char* wsb = (char*)wsf;

    // ========== P0: weight images + b3-node tables (blocks 0-127) | r-stats+deg (128-255) ==========
    int t512 = blk * 512 + tid;
    if (t512 < 65536) {
        if (t512 < 4096) {   // W2T [p][c][k] <- rw2 [p][k][c]
            int p = t512 >> 10, rem = t512 & 1023, c = rem >> 5, k = rem & 31;
            wsf[WS_W2T + t512] = rw2[(p << 10) + (k << 5) + c];
        }
        if (t512 < 16384) {  // image A
            int col = t512 >> 5, k = t512 & 31;
            float v = (col < 256) ? w300[(k << 8) + col] : w310[(k << 8) + (col - 256)];
            ((unsigned short*)(wsb + WSB_WA))[t512] = f2bf(v);
        }
        if (t512 < 8192) {   // image B
            int col = t512 >> 5, k = t512 & 31;
            ((unsigned short*)(wsb + WSB_WB))[t512] = f2bf(w301[(k << 8) + col]);
        }
        if (t512 < 24576) {  // image C f-major
            int col = t512 >> 5, k = t512 & 31;
            int f = col >> 8, rem = col & 255;
            ((unsigned short*)(wsb + WSB_WC))[t512] = f2bf(w311[k * 768 + rem * 3 + f]);
        }
        // b3-node tables: item g = t512
        int n = t512 >> 4, mo = t512 & 15;
        float h1r[48];
#pragma unroll
        for (int j = 0; j < 48; ++j) h1r[j] = h1[n * 48 + j];
        float s00 = 0.f, s01 = 0.f;
#pragma unroll
        for (int mi = 0; mi < 16; ++mi) {
            float hv = h0[n * 16 + mi];
            s00 += bw300[mo * 16 + mi] * hv;
            s01 += bw301[mo * 16 + mi] * hv;
        }
        wsf[WS_U00 + n * 16 + mo] = s00;
        wsf[WS_U01 + n * 16 + mo] = s01;
#pragma unroll
        for (int q = 0; q < 3; ++q) {
            float sv = 0.f;
#pragma unroll
            for (int mi = 0; mi < 16; ++mi)
                sv += bw310[mo * 16 + mi] * h1r[mi * 3 + q];
            wsf[WS_V10 + n * 48 + q * 16 + mo] = sv;
        }
#pragma unroll
        for (int f = 0; f < 3; ++f)
#pragma unroll
            for (int q = 0; q < 3; ++q) {
                float sv = 0.f;
#pragma unroll
                for (int mi = 0; mi < 16; ++mi)
                    sv += bw311[(mo * 16 + mi) * 3 + f] * h1r[mi * 3 + q];
                wsf[WS_W11 + n * 144 + (f * 3 + q) * 16 + mo] = sv;
            }
    } else {
        int e = t512 - 65536;
        float v = r[e];
        atomicAdd(((int*)wsf) + WS_DEG_I + edst[e], 1);
        float s = v, ss = v * v;
#pragma unroll
        for (int mk = 32; mk >= 1; mk >>= 1) {
            s  += __shfl_xor(s,  mk, 64);
            ss += __shfl_xor(ss, mk, 64);
        }
        float* ls = (float*)smem;   // 16 floats
        if (lane == 0) { ls[wv] = s; ls[8 + wv] = ss; }
        __syncthreads();
        if (tid == 0) {
            float a = 0.f, b = 0.f;
#pragma unroll
            for (int i = 0; i < 8; ++i) { a += ls[i]; b += ls[8 + i]; }
            atomicAdd(wsf + WS_RSUM, a);
            atomicAdd(wsf + WS_RSUMSQ, b);
        }
    }
    grid.sync();

    // ========== P1: y1 Gram + y1 sum via MFMA (256 edges/block, 8 ks iters) ==========
    {
        int p  = __builtin_amdgcn_readfirstlane(wv & 3);
        int mt = __builtin_amdgcn_readfirstlane(wv >> 2);
        float mu_r  = wsf[WS_RSUM] * (1.f / N_EDGES);
        float var_r = wsf[WS_RSUMSQ] * (1.f / N_EDGES) - mu_r * mu_r;
        float al[2], be[2];
#pragma unroll
        for (int hh = 0; hh < 2; ++hh) {
            int ch = p * 32 + hh * 16 + lq;
            float w1 = rw1[ch];
            float a = w1 * rg1[ch] * rsqrtf(w1 * w1 * var_r + BN_EPS);
            al[hh] = a;
            be[hh] = rbe1[ch] - a * mu_r;
        }
        bf16x8 ones;
#pragma unroll
        for (int j = 0; j < 8; ++j) ones[j] = (short)0x3F80;
        f32x4 accG0 = {0.f, 0.f, 0.f, 0.f};
        f32x4 accG1 = {0.f, 0.f, 0.f, 0.f};
        f32x4 accS  = {0.f, 0.f, 0.f, 0.f};
        int ebase = blk * 256;
#pragma unroll 1
        for (int ks = 0; ks < 8; ++ks) {
            const float* rp = r + ebase + ks * 32 + quad * 8;
            float4 ra = *(const float4*)(rp);
            float4 rb = *(const float4*)(rp + 4);
            float rv[8] = {ra.x, ra.y, ra.z, ra.w, rb.x, rb.y, rb.z, rb.w};
            bf16x8 fr0, fr1;
#pragma unroll
            for (int j = 0; j < 8; ++j) {
                fr0[j] = (short)f2bf(fmaxf(0.f, al[0] * rv[j] + be[0]));
                fr1[j] = (short)f2bf(fmaxf(0.f, al[1] * rv[j] + be[1]));
            }
            bf16x8 fA = mt ? fr1 : fr0;
            accG0 = __builtin_amdgcn_mfma_f32_16x16x32_bf16(fA, fr0, accG0, 0, 0, 0);
            accG1 = __builtin_amdgcn_mfma_f32_16x16x32_bf16(fA, fr1, accG1, 0, 0, 0);
            accS  = __builtin_amdgcn_mfma_f32_16x16x32_bf16(fA, ones, accS,  0, 0, 0);
        }
        float* G = wsf + WS_GRAM + p * 1024;
#pragma unroll
        for (int reg = 0; reg < 4; ++reg) {
            int k1 = mt * 16 + quad * 4 + reg;
            atomicAdd(&G[k1 * 32 + lq],      accG0[reg]);
            atomicAdd(&G[k1 * 32 + 16 + lq], accG1[reg]);
        }
        if (lq == 0) {
#pragma unroll
            for (int reg = 0; reg < 4; ++reg)
                atomicAdd(wsf + WS_SUMY + p * 32 + mt * 16 + quad * 4 + reg, accS[reg]);
        }
    }
    grid.sync();

    // ========== P2: finalize BN params + prefix scan (block 0 only) ==========
    if (blk == 0) {
        if (tid < 128) {
            float mu_r  = wsf[WS_RSUM] * (1.f / N_EDGES);
            float var_r = wsf[WS_RSUMSQ] * (1.f / N_EDGES) - mu_r * mu_r;
            float w1 = rw1[tid];
            float al = w1 * rg1[tid] * rsqrtf(w1 * w1 * var_r + BN_EPS);
            wsf[WS_ALPHA1 + tid] = al;
            wsf[WS_BETA1  + tid] = rbe1[tid] - al * mu_r;
            int p = tid >> 5, c = tid & 31;
            const float* G = wsf + WS_GRAM + p * 1024;
            const float* w = wsf + WS_W2T + p * 1024 + c * 32;
            float invE = 1.f / N_EDGES;
            float s1 = 0.f;
#pragma unroll 1
            for (int k = 0; k < 32; ++k) s1 += w[k] * (wsf[WS_SUMY + p * 32 + k] * invE);
            float q = 0.f;
#pragma unroll 1
            for (int k1 = 0; k1 < 32; ++k1) {
                float a = 0.f;
#pragma unroll
                for (int k2 = 0; k2 < 32; ++k2) a += w[k2] * G[k1 * 32 + k2];
                q += w[k1] * a;
            }
            float var = q * invE - s1 * s1;
            float a2 = rg2[tid] * rsqrtf(var + BN_EPS);
            wsf[WS_A2 + tid] = a2;
            float mu2 = rb2[tid] + s1;
            wsf[WS_S2 + tid] = rbe2[tid] - mu2 * a2;
        }
        int* sdata = (int*)smem;
        const int* deg = ((const int*)wsf) + WS_DEG_I;
        int* offs = ((int*)wsf) + WS_OFFS_I;
        int* cur  = ((int*)wsf) + WS_CUR_I;
        int base = tid * 8;
        int v[8]; int ssum = 0;
#pragma unroll
        for (int j = 0; j < 8; ++j) { v[j] = deg[base + j]; ssum += v[j]; }
        sdata[tid] = ssum;
        __syncthreads();
        for (int off = 1; off < 512; off <<= 1) {
            int x = sdata[tid];
            int y = (tid >= off) ? sdata[tid - off] : 0;
            __syncthreads();
            sdata[tid] = x + y;
            __syncthreads();
        }
        int run = (tid == 0) ? 0 : sdata[tid - 1];
#pragma unroll
        for (int j = 0; j < 8; ++j) { offs[base + j] = run; cur[base + j] = run; run += v[j]; }
        if (tid == 511) offs[4096] = sdata[511];
    }
    grid.sync();

    // ========== P3: bucket + msg bias-correction init ==========
    if (tid < 256) {
        int e = blk * 256 + tid;
        int d = edst[e];
        int pos = atomicAdd(((int*)wsf) + WS_CUR_I + d, 1);
        (((int*)wsf) + WS_ELIST_I)[pos] = e;
    }
#pragma unroll 1
    for (int it = 0; it < 2; ++it) {
        int g = blk * 1024 + it * 512 + tid;
        int e = g >> 2, cq = g & 3;
        int s = esrc[e];
        float4 u00q = *(const float4*)(wsf + WS_U00 + s * 16 + cq * 4);
        float b00v = b00[e];
        float m0[4];
#pragma unroll
        for (int rr = 0; rr < 4; ++rr) m0[rr] = b00v * ((const float*)&u00q)[rr];
#pragma unroll
        for (int q = 0; q < 3; ++q) {
            float4 vq = *(const float4*)(wsf + WS_V10 + s * 48 + q * 16 + cq * 4);
            float bq = b10[e * 3 + q];
#pragma unroll
            for (int rr = 0; rr < 4; ++rr) m0[rr] += bq * ((const float*)&vq)[rr];
        }
        {
            float4 w = {m0[0], m0[1], m0[2], m0[3]};
            *(float4*)(msg + (size_t)e * 64 + cq * 4) = w;
        }
        float4 u01q = *(const float4*)(wsf + WS_U01 + s * 16 + cq * 4);
        float bo0 = b01[e * 3 + 0], bo1 = b01[e * 3 + 1], bo2 = b01[e * 3 + 2];
        float m1[4][3];
#pragma unroll
        for (int rr = 0; rr < 4; ++rr) {
            float u = ((const float*)&u01q)[rr];
            m1[rr][0] = bo0 * u; m1[rr][1] = bo1 * u; m1[rr][2] = bo2 * u;
        }
#pragma unroll
        for (int f = 0; f < 3; ++f)
#pragma unroll
            for (int q = 0; q < 3; ++q) {
                float4 wq = *(const float4*)(wsf + WS_W11 + s * 144 + (f * 3 + q) * 16 + cq * 4);
#pragma unroll
                for (int o = 0; o < 3; ++o) {
                    float bas = b11[e * 27 + o * 9 + q * 3 + f];
#pragma unroll
                    for (int rr = 0; rr < 4; ++rr) m1[rr][o] += bas * ((const float*)&wq)[rr];
                }
            }
        float* base = msg + (size_t)e * 64 + 16 + cq * 12;
        float4 w0 = {m1[0][0], m1[0][1], m1[0][2], m1[1][0]};
        float4 w1 = {m1[1][1], m1[1][2], m1[2][0], m1[2][1]};
        float4 w2 = {m1[2][2], m1[3][0], m1[3][1], m1[3][2]};
        *(float4*)(base)     = w0;
        *(float4*)(base + 4) = w1;
        *(float4*)(base + 8) = w2;
    }
    grid.sync();

    // ========== P4: MFMA message kernel (r15 body verbatim) ==========
    {
        short* w3s = (short*)smem;
        int eb = blk << 8;
        // Phase A: pairs 00 + 10 -> msg0 (RMW)
        {
            const float4* src = (const float4*)(wsb + WSB_WA);
            float4* dst = (float4*)smem;
#pragma unroll
            for (int i = 0; i < 4; ++i) dst[i * 512 + tid] = src[i * 512 + tid];
        }
        {
            int p = __builtin_amdgcn_readfirstlane((tid >> 8) * 2);
            int el = tid & 255;
            float rv = r[eb + el];
            char* dst = smem + 32768 + (tid >> 8) * 16384;
            y2_lds16(p, el, 0, rv, wsf, rb2, dst);
            y2_lds16(p, el, 16, rv, wsf, rb2, dst);
        }
        __syncthreads();
#pragma unroll
        for (int g2 = 0; g2 < 2; ++g2) {
            int el = (wv * 2 + g2) * 16 + lq;
            int e = eb + el;
            int s = esrc[e];
            bf16x8 bf0 = *(const bf16x8*)(smem + 32768 + el * 64 + quad * 16);
            bf16x8 bf2 = *(const bf16x8*)(smem + 49152 + el * 64 + quad * 16);
            float4 h0q = *(const float4*)(h0 + s * 16 + quad * 4);
            float4 hv0 = *(const float4*)(h1 + s * 48 + quad * 12);
            float4 hv1 = *(const float4*)(h1 + s * 48 + quad * 12 + 4);
            float4 hv2 = *(const float4*)(h1 + s * 48 + quad * 12 + 8);
            float b00v = b00[e];
            float bq0 = b10[e * 3 + 0], bq1 = b10[e * 3 + 1], bq2 = b10[e * 3 + 2];
            float gq0 = bq0 * hv0.x + bq1 * hv0.y + bq2 * hv0.z;
            float gq1 = bq0 * hv0.w + bq1 * hv1.x + bq2 * hv1.y;
            float gq2 = bq0 * hv1.z + bq1 * hv1.w + bq2 * hv2.x;
            float gq3 = bq0 * hv2.y + bq1 * hv2.z + bq2 * hv2.w;
            float4 a0v = *(const float4*)(msg + (size_t)e * 64 + quad * 4);
            float a0[4] = {a0v.x, a0v.y, a0v.z, a0v.w};
#pragma unroll
            for (int m = 0; m < 16; ++m) {
                bf16x8 af = *(const bf16x8*)(w3s + (m * 16 + lq) * 32 + quad * 8);
                f32x4 dd = __builtin_amdgcn_mfma_f32_16x16x32_bf16(af, bf0, (f32x4){0.f,0.f,0.f,0.f}, 0, 0, 0);
                float partial = dd[0] * h0q.x + dd[1] * h0q.y + dd[2] * h0q.z + dd[3] * h0q.w;
                partial += __shfl_xor(partial, 16);
                partial += __shfl_xor(partial, 32);
                a0[m & 3] += (quad == (m >> 2)) ? b00v * partial : 0.f;
            }
#pragma unroll
            for (int m = 0; m < 16; ++m) {
                bf16x8 af = *(const bf16x8*)(w3s + ((256 + m * 16 + lq) << 5) + quad * 8);
                f32x4 dd = __builtin_amdgcn_mfma_f32_16x16x32_bf16(af, bf2, (f32x4){0.f,0.f,0.f,0.f}, 0, 0, 0);
                float partial = dd[0] * gq0 + dd[1] * gq1 + dd[2] * gq2 + dd[3] * gq3;
                partial += __shfl_xor(partial, 16);
                partial += __shfl_xor(partial, 32);
                a0[m & 3] += (quad == (m >> 2)) ? partial : 0.f;
            }
            float4 w = {a0[0], a0[1], a0[2], a0[3]};
            *(float4*)(msg + (size_t)e * 64 + quad * 4) = w;
        }
        __syncthreads();
        // Phase B: pair 01 -> msg1 += b01 (x) d01 (RMW)
        {
            const float4* src = (const float4*)(wsb + WSB_WB);
            float4* dst = (float4*)smem;
#pragma unroll
            for (int i = 0; i < 2; ++i) dst[i * 512 + tid] = src[i * 512 + tid];
        }
        {
            int el = tid & 255, c0 = (tid >> 8) * 16;
            y2_lds16(1, el, c0, r[eb + el], wsf, rb2, smem + 16384);
        }
        __syncthreads();
#pragma unroll
        for (int g2 = 0; g2 < 2; ++g2) {
            int el = (wv * 2 + g2) * 16 + lq;
            int e = eb + el;
            int s = esrc[e];
            bf16x8 bf1 = *(const bf16x8*)(smem + 16384 + el * 64 + quad * 16);
            float4 h0q = *(const float4*)(h0 + s * 16 + quad * 4);
            float d1[4] = {0.f, 0.f, 0.f, 0.f};
#pragma unroll
            for (int m = 0; m < 16; ++m) {
                bf16x8 af = *(const bf16x8*)(w3s + (m * 16 + lq) * 32 + quad * 8);
                f32x4 dd = __builtin_amdgcn_mfma_f32_16x16x32_bf16(af, bf1, (f32x4){0.f,0.f,0.f,0.f}, 0, 0, 0);
                float partial = dd[0] * h0q.x + dd[1] * h0q.y + dd[2] * h0q.z + dd[3] * h0q.w;
                partial += __shfl_xor(partial, 16);
                partial += __shfl_xor(partial, 32);
                d1[m & 3] += (quad == (m >> 2)) ? partial : 0.f;
            }
            float bo0 = b01[e * 3 + 0], bo1 = b01[e * 3 + 1], bo2 = b01[e * 3 + 2];
            float* base = msg + (size_t)e * 64 + 16 + quad * 12;
            float4 r0 = *(const float4*)(base);
            float4 r1 = *(const float4*)(base + 4);
            float4 r2 = *(const float4*)(base + 8);
            float4 w0 = {r0.x + bo0 * d1[0], r0.y + bo1 * d1[0], r0.z + bo2 * d1[0], r0.w + bo0 * d1[1]};
            float4 w1 = {r1.x + bo1 * d1[1], r1.y + bo2 * d1[1], r1.z + bo0 * d1[2], r1.w + bo1 * d1[2]};
            float4 w2 = {r2.x + bo2 * d1[2], r2.y + bo0 * d1[3], r2.z + bo1 * d1[3], r2.w + bo2 * d1[3]};
            *(float4*)(base)     = w0;
            *(float4*)(base + 4) = w1;
            *(float4*)(base + 8) = w2;
        }
        __syncthreads();
        // Phase C: pair 11 -> msg1 += (RMW)
        {
            const float4* src = (const float4*)(wsb + WSB_WC);
            float4* dst = (float4*)smem;
#pragma unroll
            for (int i = 0; i < 6; ++i) dst[i * 512 + tid] = src[i * 512 + tid];
        }
        {
            int el = tid & 255, c0 = (tid >> 8) * 16;
            y2_lds16(3, el, c0, r[eb + el], wsf, rb2, smem + 49152);
        }
        __syncthreads();
#pragma unroll
        for (int g2 = 0; g2 < 2; ++g2) {
            int el = (wv * 2 + g2) * 16 + lq;
            int e = eb + el;
            int s = esrc[e];
            bf16x8 bf3 = *(const bf16x8*)(smem + 49152 + el * 64 + quad * 16);
            float4 hv0 = *(const float4*)(h1 + s * 48 + quad * 12);
            float4 hv1 = *(const float4*)(h1 + s * 48 + quad * 12 + 4);
            float4 hv2 = *(const float4*)(h1 + s * 48 + quad * 12 + 8);
            float h1v[4][3] = {{hv0.x, hv0.y, hv0.z}, {hv0.w, hv1.x, hv1.y},
                               {hv1.z, hv1.w, hv2.x}, {hv2.y, hv2.z, hv2.w}};
            float m1[4][3];
#pragma unroll
            for (int rr = 0; rr < 4; ++rr)
#pragma unroll
                for (int o = 0; o < 3; ++o) m1[rr][o] = 0.f;
#pragma unroll
            for (int f = 0; f < 3; ++f) {
                float Tf[4][3];
#pragma unroll
                for (int o = 0; o < 3; ++o) {
                    float bv0 = b11[e * 27 + o * 9 + 0 + f];
                    float bv1 = b11[e * 27 + o * 9 + 3 + f];
                    float bv2 = b11[e * 27 + o * 9 + 6 + f];
#pragma unroll
                    for (int rr = 0; rr < 4; ++rr)
                        Tf[rr][o] = h1v[rr][0] * bv0 + h1v[rr][1] * bv1 + h1v[rr][2] * bv2;
                }
#pragma unroll
                for (int m = 0; m < 16; ++m) {
                    int colb = f * 256 + m * 16 + lq;
                    bf16x8 af = *(const bf16x8*)(w3s + colb * 32 + quad * 8);
                    f32x4 dd = __builtin_amdgcn_mfma_f32_16x16x32_bf16(af, bf3, (f32x4){0.f,0.f,0.f,0.f}, 0, 0, 0);
#pragma unroll
                    for (int o = 0; o < 3; ++o) {
                        float po = dd[0] * Tf[0][o] + dd[1] * Tf[1][o] + dd[2] * Tf[2][o] + dd[3] * Tf[3][o];
                        po += __shfl_xor(po, 16);
                        po += __shfl_xor(po, 32);
                        m1[m & 3][o] += (quad == (m >> 2)) ? po : 0.f;
                    }
                }
            }
            float* base = msg + (size_t)e * 64 + 16 + quad * 12;
            float4 r0 = *(const float4*)(base);
            float4 r1 = *(const float4*)(base + 4);
            float4 r2 = *(const float4*)(base + 8);
            float4 w0 = {m1[0][0] + r0.x, m1[0][1] + r0.y, m1[0][2] + r0.z, m1[1][0] + r0.w};
            float4 w1 = {m1[1][1] + r1.x, m1[1][2] + r1.y, m1[2][0] + r1.z, m1[2][1] + r1.w};
            float4 w2 = {m1[2][2] + r2.x, m1[3][0] + r2.y, m1[3][1] + r2.z, m1[3][2] + r2.w};
            *(float4*)(base)     = w0;
            *(float4*)(base + 4) = w1;
            *(float4*)(base + 8) = w2;
        }
    }
    grid.sync();

    // ========== P5: gather per node, /cnt, + self-interaction (2 nodes/wave) ==========
    {
        const int* offs  = ((const int*)wsf) + WS_OFFS_I;
        const int* elist = ((const int*)wsf) + WS_ELIST_I;
        const float* msgr = msg;
#pragma unroll 1
        for (int nn = 0; nn < 2; ++nn) {
            int n = blk * 16 + wv * 2 + nn;
            int start = offs[n], end = offs[n + 1];
            int deg = end - start;
            float acc = 0.f;
            for (int j0 = 0; j0 < deg; j0 += 64) {
                int cnt = min(64, deg - j0);
                int eidv = (j0 + lane < deg) ? elist[start + j0 + lane] : 0;
                int jj = 0;
                for (; jj + 3 < cnt; jj += 4) {
                    int e0 = __shfl(eidv, jj), e1 = __shfl(eidv, jj + 1);
                    int e2 = __shfl(eidv, jj + 2), e3 = __shfl(eidv, jj + 3);
                    float v0 = msgr[(size_t)e0 * 64 + lane];
                    float v1 = msgr[(size_t)e1 * 64 + lane];
                    float v2 = msgr[(size_t)e2 * 64 + lane];
                    float v3 = msgr[(size_t)e3 * 64 + lane];
                    acc += (v0 + v1) + (v2 + v3);
                }
                for (; jj < cnt; ++jj) {
                    int eid = __shfl(eidv, jj);
                    acc += msgr[(size_t)eid * 64 + lane];
                }
            }
            float self = 0.f;
            if (lane < 16) {
                int m = lane;
#pragma unroll
                for (int i = 0; i < 16; ++i) self += Wself0[m * 16 + i] * h0[n * 16 + i];
            } else {
                int idx = lane - 16; int m = idx / 3, o = idx % 3;
#pragma unroll
                for (int i = 0; i < 16; ++i) self += Wself1[m * 16 + i] * h1[n * 48 + i * 3 + o];
            }
            float c = (float)(deg > 0 ? deg : 1);
            float res = acc / c + (deg > 0 ? self : 0.f);
            if (lane < 16) out[n * 16 + lane] = res;
            else           out[65536 + n * 48 + (lane - 16)] = res;
        }
    }
}

extern "C" void kernel_launch(void* const* d_in, const int* in_sizes, int n_in,
                              void* d_out, int out_size, void* d_ws, size_t ws_size,
                              hipStream_t stream) {
    const float* h0   = (const float*)d_in[0];
    const float* h1   = (const float*)d_in[1];
    const float* r    = (const float*)d_in[2];
    const float* b00  = (const float*)d_in[3];
    const float* b01  = (const float*)d_in[4];
    const float* b10  = (const float*)d_in[5];
    const float* b11  = (const float*)d_in[6];
    const float* rw1  = (const float*)d_in[7];
    // d_in[8] = rb1: cancels inside BatchNorm
    const float* rg1  = (const float*)d_in[9];
    const float* rbe1 = (const float*)d_in[10];
    const float* rw2  = (const float*)d_in[11];
    const float* rb2  = (const float*)d_in[12];
    const float* rg2  = (const float*)d_in[13];
    const float* rbe2 = (const float*)d_in[14];
    const float* w300 = (const float*)d_in[15];
    const float* bw300= (const float*)d_in[16];
    const float* w301 = (const float*)d_in[17];
    const float* bw301= (const float*)d_in[18];
    const float* w310 = (const float*)d_in[19];
    const float* bw310= (const float*)d_in[20];
    const float* w311 = (const float*)d_in[21];
    const float* bw311= (const float*)d_in[22];
    const float* Wself0 = (const float*)d_in[23];
    const float* Wself1 = (const float*)d_in[24];
    const int* esrc = (const int*)d_in[25];
    const int* edst = (const int*)d_in[26];
    float* out = (float*)d_out;
    float* wsf = (float*)d_ws;
    float* msg = wsf + WS_MSG_F;

    static bool attr_set = false;
    if (!attr_set) {
        hipFuncSetAttribute((const void*)k_all,
                            hipFuncAttributeMaxDynamicSharedMemorySize, 65536);
        attr_set = true;
    }

    // single memset: stats + deg + Gram + SUMY (bytes 0..37376)
    hipMemsetAsync(d_ws, 0, 37376, stream);

    void* args[] = {
        (void*)&rw2, (void*)&w300, (void*)&w301, (void*)&w310, (void*)&w311,
        (void*)&bw300, (void*)&bw301, (void*)&bw310, (void*)&bw311,
        (void*)&r, (void*)&edst, (void*)&esrc, (void*)&h0, (void*)&h1,
        (void*)&b00, (void*)&b01, (void*)&b10, (void*)&b11,
        (void*)&rw1, (void*)&rg1, (void*)&rbe1, (void*)&rb2,
        (void*)&rg2, (void*)&rbe2, (void*)&Wself0, (void*)&Wself1,
        (void*)&wsf, (void*)&msg, (void*)&out
    };
    hipLaunchCooperativeKernel((const void*)k_all, dim3(256), dim3(512),
                               args, 65536, stream);
}

// Round 18
// 248.724 us; speedup vs baseline: 1.8156x; 1.8156x over previous
//
#include <hip/hip_runtime.h>

#define N_NODES 4096
#define N_EDGES 65536
#define MID 32
#define BN_EPS 1e-5f

// ---- workspace layout ----
// float offsets:
#define WS_RSUM    0
#define WS_RSUMSQ  1
#define WS_ALPHA1  272
#define WS_BETA1   400
#define WS_A2      528
#define WS_S2      656
#define WS_GRAM    5120   // floats 5120..9215
#define WS_SUMY    9216   // floats 9216..9343
#define WS_W2T     17664  // [4][32][32] fp32 (p,c,k)
#define WS_MSG_F   262144 // [E][64] fp32 messages (byte 1048576)
#define WS_U00     4456448 // [N][16]  b3_00 @ h0
#define WS_U01     4521984 // [N][16]  b3_01 @ h0
#define WS_V10     4587520 // [N][3q][16m] b3_10 @ h1
#define WS_W11     4784128 // [N][3f*3q][16m] b3_11 @ h1
// int offsets:
#define WS_DEG_I   1024   // ints 1024..5119
#define WS_CUR_I   9344   // ints 9344..13439
#define WS_OFFS_I  13440  // ints 13440..17536
#define WS_ELIST_I 65536  // ints 65536..131071
// byte offsets (weight images, chunk-swizzled: 16B chunk c of col at slot ((col>>1)+c)&3):
#define WSB_WA     524288 // 512 cols x 32 bf16 (32 KB)
#define WSB_WB     557056 // 256 cols p01 (16 KB)
#define WSB_WC     573440 // 768 cols p11 f-major (48 KB)

typedef short bf16x8 __attribute__((ext_vector_type(8)));
typedef float f32x4  __attribute__((ext_vector_type(4)));

__device__ __forceinline__ unsigned short f2bf(float x) {
    unsigned u = __float_as_uint(x);
    u += 0x7fffu + ((u >> 16) & 1u);   // RNE
    return (unsigned short)(u >> 16);
}

// swizzled short-index for element (col, k) of a weight image:
// chunk = k>>3 stored at slot ((col>>1)+chunk)&3
__device__ __forceinline__ int wimg_idx(int col, int k) {
    return col * 32 + ((((col >> 1) + (k >> 3)) & 3) << 3) + (k & 7);
}

// ---------- K1: prep (0-127) + r-stats/degree (128-383) + b3-node tables (384-639) ----------
__global__ void __launch_bounds__(256) k_pre(const float* __restrict__ rw2,
        const float* __restrict__ w300, const float* __restrict__ w301,
        const float* __restrict__ w310, const float* __restrict__ w311,
        const float* __restrict__ bw300, const float* __restrict__ bw301,
        const float* __restrict__ bw310, const float* __restrict__ bw311,
        const float* __restrict__ r, const int* __restrict__ edst,
        const float* __restrict__ h0, const float* __restrict__ h1,
        float* __restrict__ wsf) {
    if (blockIdx.x < 128) {
        int t = blockIdx.x * 256 + threadIdx.x;   // 0..32767
        char* wsb = (char*)wsf;
        if (t < 4096) {   // W2T [p][c][k] <- rw2 [p][k][c]
            int p = t >> 10, rem = t & 1023, c = rem >> 5, k = rem & 31;
            wsf[WS_W2T + t] = rw2[(p << 10) + (k << 5) + c];
        }
        if (t < 16384) {  // image A: p00 | p10 (swizzled)
            int col = t >> 5, k = t & 31;
            float v = (col < 256) ? w300[(k << 8) + col] : w310[(k << 8) + (col - 256)];
            ((unsigned short*)(wsb + WSB_WA))[wimg_idx(col, k)] = f2bf(v);
        }
        if (t < 8192) {   // image B: p01 (swizzled)
            int col = t >> 5, k = t & 31;
            ((unsigned short*)(wsb + WSB_WB))[wimg_idx(col, k)] = f2bf(w301[(k << 8) + col]);
        }
        if (t < 24576) {  // image C: p11 f-major (swizzled)
            int col = t >> 5, k = t & 31;
            int f = col >> 8, rem = col & 255;
            ((unsigned short*)(wsb + WSB_WC))[wimg_idx(col, k)] = f2bf(w311[k * 768 + rem * 3 + f]);
        }
    } else if (blockIdx.x < 384) {
        int e = (blockIdx.x - 128) * 256 + threadIdx.x;   // 0..65535
        float v = r[e];
        atomicAdd(((int*)wsf) + WS_DEG_I + edst[e], 1);
        float s = v, ss = v * v;
#pragma unroll
        for (int mk = 32; mk >= 1; mk >>= 1) {
            s  += __shfl_xor(s,  mk, 64);
            ss += __shfl_xor(ss, mk, 64);
        }
        __shared__ float ls[4], lss[4];
        int lane = threadIdx.x & 63, wv = threadIdx.x >> 6;
        if (lane == 0) { ls[wv] = s; lss[wv] = ss; }
        __syncthreads();
        if (threadIdx.x == 0) {
            atomicAdd(wsf + WS_RSUM,   ls[0] + ls[1] + ls[2] + ls[3]);
            atomicAdd(wsf + WS_RSUMSQ, lss[0] + lss[1] + lss[2] + lss[3]);
        }
    } else {
        int g = (blockIdx.x - 384) * 256 + threadIdx.x;   // 0..65535
        int n = g >> 4, mo = g & 15;
        float h1r[48];
#pragma unroll
        for (int j = 0; j < 48; ++j) h1r[j] = h1[n * 48 + j];
        float s00 = 0.f, s01 = 0.f;
#pragma unroll
        for (int mi = 0; mi < 16; ++mi) {
            float hv = h0[n * 16 + mi];
            s00 += bw300[mo * 16 + mi] * hv;
            s01 += bw301[mo * 16 + mi] * hv;
        }
        wsf[WS_U00 + n * 16 + mo] = s00;
        wsf[WS_U01 + n * 16 + mo] = s01;
#pragma unroll
        for (int q = 0; q < 3; ++q) {
            float sv = 0.f;
#pragma unroll
            for (int mi = 0; mi < 16; ++mi)
                sv += bw310[mo * 16 + mi] * h1r[mi * 3 + q];
            wsf[WS_V10 + n * 48 + q * 16 + mo] = sv;
        }
#pragma unroll
        for (int f = 0; f < 3; ++f)
#pragma unroll
            for (int q = 0; q < 3; ++q) {
                float sv = 0.f;
#pragma unroll
                for (int mi = 0; mi < 16; ++mi)
                    sv += bw311[(mo * 16 + mi) * 3 + f] * h1r[mi * 3 + q];
                wsf[WS_W11 + n * 144 + (f * 3 + q) * 16 + mo] = sv;
            }
    }
}

// ---------- K2: y1 Gram + y1 sum via MFMA ----------
__global__ void __launch_bounds__(512) k_gram(const float* __restrict__ r,
        const float* __restrict__ rw1, const float* __restrict__ rg1,
        const float* __restrict__ rbe1, float* __restrict__ wsf) {
    int t = threadIdx.x;
    int wv = t >> 6, lane = t & 63;
    int quad = lane >> 4, lq = lane & 15;
    int p  = __builtin_amdgcn_readfirstlane(wv & 3);
    int mt = __builtin_amdgcn_readfirstlane(wv >> 2);
    float mu_r  = wsf[WS_RSUM] * (1.f / N_EDGES);
    float var_r = wsf[WS_RSUMSQ] * (1.f / N_EDGES) - mu_r * mu_r;
    float al[2], be[2];
#pragma unroll
    for (int hh = 0; hh < 2; ++hh) {
        int ch = p * 32 + hh * 16 + lq;
        float w1 = rw1[ch];
        float a = w1 * rg1[ch] * rsqrtf(w1 * w1 * var_r + BN_EPS);
        al[hh] = a;
        be[hh] = rbe1[ch] - a * mu_r;
    }
    bf16x8 ones;
#pragma unroll
    for (int j = 0; j < 8; ++j) ones[j] = (short)0x3F80;
    f32x4 accG0 = {0.f, 0.f, 0.f, 0.f};
    f32x4 accG1 = {0.f, 0.f, 0.f, 0.f};
    f32x4 accS  = {0.f, 0.f, 0.f, 0.f};
    int ebase = blockIdx.x * 512;   // grid 128
#pragma unroll 1
    for (int ks = 0; ks < 16; ++ks) {
        const float* rp = r + ebase + ks * 32 + quad * 8;
        float4 ra = *(const float4*)(rp);
        float4 rb = *(const float4*)(rp + 4);
        float rv[8] = {ra.x, ra.y, ra.z, ra.w, rb.x, rb.y, rb.z, rb.w};
        bf16x8 fr0, fr1;
#pragma unroll
        for (int j = 0; j < 8; ++j) {
            fr0[j] = (short)f2bf(fmaxf(0.f, al[0] * rv[j] + be[0]));
            fr1[j] = (short)f2bf(fmaxf(0.f, al[1] * rv[j] + be[1]));
        }
        bf16x8 fA = mt ? fr1 : fr0;
        accG0 = __builtin_amdgcn_mfma_f32_16x16x32_bf16(fA, fr0, accG0, 0, 0, 0);
        accG1 = __builtin_amdgcn_mfma_f32_16x16x32_bf16(fA, fr1, accG1, 0, 0, 0);
        accS  = __builtin_amdgcn_mfma_f32_16x16x32_bf16(fA, ones, accS,  0, 0, 0);
    }
    float* G = wsf + WS_GRAM + p * 1024;
#pragma unroll
    for (int reg = 0; reg < 4; ++reg) {
        int k1 = mt * 16 + quad * 4 + reg;
        atomicAdd(&G[k1 * 32 + lq],      accG0[reg]);
        atomicAdd(&G[k1 * 32 + 16 + lq], accG1[reg]);
    }
    if (lq == 0) {
#pragma unroll
        for (int reg = 0; reg < 4; ++reg)
            atomicAdd(wsf + WS_SUMY + p * 32 + mt * 16 + quad * 4 + reg, accS[reg]);
    }
}

// ---------- K3: fused finalize + prefix scan ----------
__global__ void __launch_bounds__(1024) k_fs(const float* __restrict__ rw1,
        const float* __restrict__ rg1, const float* __restrict__ rbe1,
        const float* __restrict__ rg2, const float* __restrict__ rbe2,
        const float* __restrict__ rb2, float* __restrict__ wsf) {
    int t = threadIdx.x;
    if (t < 128) {
        float mu_r  = wsf[WS_RSUM] * (1.f / N_EDGES);
        float var_r = wsf[WS_RSUMSQ] * (1.f / N_EDGES) - mu_r * mu_r;
        float w1 = rw1[t];
        float al = w1 * rg1[t] * rsqrtf(w1 * w1 * var_r + BN_EPS);
        wsf[WS_ALPHA1 + t] = al;
        wsf[WS_BETA1  + t] = rbe1[t] - al * mu_r;
        int p = t >> 5, c = t & 31;
        const float* G = wsf + WS_GRAM + p * 1024;
        const float* w = wsf + WS_W2T + p * 1024 + c * 32;
        float invE = 1.f / N_EDGES;
        float s1 = 0.f;
#pragma unroll 1
        for (int k = 0; k < 32; ++k) s1 += w[k] * (wsf[WS_SUMY + p * 32 + k] * invE);
        float q = 0.f;
#pragma unroll 1
        for (int k1 = 0; k1 < 32; ++k1) {
            float a = 0.f;
#pragma unroll
            for (int k2 = 0; k2 < 32; ++k2) a += w[k2] * G[k1 * 32 + k2];
            q += w[k1] * a;
        }
        float var = q * invE - s1 * s1;
        float a2 = rg2[t] * rsqrtf(var + BN_EPS);
        wsf[WS_A2 + t] = a2;
        float mu2 = rb2[t] + s1;
        wsf[WS_S2 + t] = rbe2[t] - mu2 * a2;
    }
    __shared__ int sdata[1024];
    const int* deg = ((const int*)wsf) + WS_DEG_I;
    int* offs = ((int*)wsf) + WS_OFFS_I;
    int* cur  = ((int*)wsf) + WS_CUR_I;
    int v0 = deg[t * 4], v1 = deg[t * 4 + 1], v2 = deg[t * 4 + 2], v3 = deg[t * 4 + 3];
    sdata[t] = v0 + v1 + v2 + v3;
    __syncthreads();
    for (int off = 1; off < 1024; off <<= 1) {
        int x = sdata[t];
        int y = (t >= off) ? sdata[t - off] : 0;
        __syncthreads();
        sdata[t] = x + y;
        __syncthreads();
    }
    int excl = (t == 0) ? 0 : sdata[t - 1];
    int o0 = excl, o1 = excl + v0, o2 = o1 + v1, o3 = o2 + v2;
    offs[t * 4] = o0;     cur[t * 4] = o0;
    offs[t * 4 + 1] = o1; cur[t * 4 + 1] = o1;
    offs[t * 4 + 2] = o2; cur[t * 4 + 2] = o2;
    offs[t * 4 + 3] = o3; cur[t * 4 + 3] = o3;
    if (t == 1023) offs[4096] = sdata[1023];
}

// ---------- K4: fused bucket (blocks 0-255) + msg bias-correction init (256-1279) ----------
__global__ void __launch_bounds__(256) k_cb(const int* __restrict__ edst,
        const float* __restrict__ b00, const float* __restrict__ b01,
        const float* __restrict__ b10, const float* __restrict__ b11,
        const int* __restrict__ esrc, float* __restrict__ wsf,
        float* __restrict__ msg) {
    if (blockIdx.x < 256) {
        int e = blockIdx.x * 256 + threadIdx.x;
        int d = edst[e];
        int* cur   = ((int*)wsf) + WS_CUR_I;
        int* elist = ((int*)wsf) + WS_ELIST_I;
        int pos = atomicAdd(&cur[d], 1);
        elist[pos] = e;
        return;
    }
    int g = (blockIdx.x - 256) * 256 + threadIdx.x;   // 0..262143
    int e = g >> 2, quad = g & 3;
    int s = esrc[e];
    float4 u00q = *(const float4*)(wsf + WS_U00 + s * 16 + quad * 4);
    float b00v = b00[e];
    float m0[4];
#pragma unroll
    for (int rr = 0; rr < 4; ++rr) m0[rr] = b00v * ((const float*)&u00q)[rr];
#pragma unroll
    for (int q = 0; q < 3; ++q) {
        float4 vq = *(const float4*)(wsf + WS_V10 + s * 48 + q * 16 + quad * 4);
        float bq = b10[e * 3 + q];
#pragma unroll
        for (int rr = 0; rr < 4; ++rr) m0[rr] += bq * ((const float*)&vq)[rr];
    }
    {
        float4 w = {m0[0], m0[1], m0[2], m0[3]};
        *(float4*)(msg + (size_t)e * 64 + quad * 4) = w;
    }
    float4 u01q = *(const float4*)(wsf + WS_U01 + s * 16 + quad * 4);
    float bo0 = b01[e * 3 + 0], bo1 = b01[e * 3 + 1], bo2 = b01[e * 3 + 2];
    float m1[4][3];
#pragma unroll
    for (int rr = 0; rr < 4; ++rr) {
        float u = ((const float*)&u01q)[rr];
        m1[rr][0] = bo0 * u; m1[rr][1] = bo1 * u; m1[rr][2] = bo2 * u;
    }
#pragma unroll
    for (int f = 0; f < 3; ++f)
#pragma unroll
        for (int q = 0; q < 3; ++q) {
            float4 wq = *(const float4*)(wsf + WS_W11 + s * 144 + (f * 3 + q) * 16 + quad * 4);
#pragma unroll
            for (int o = 0; o < 3; ++o) {
                float bas = b11[e * 27 + o * 9 + q * 3 + f];
#pragma unroll
                for (int rr = 0; rr < 4; ++rr) m1[rr][o] += bas * ((const float*)&wq)[rr];
            }
        }
    float* base = msg + (size_t)e * 64 + 16 + quad * 12;
    float4 w0 = {m1[0][0], m1[0][1], m1[0][2], m1[1][0]};
    float4 w1 = {m1[1][1], m1[1][2], m1[2][0], m1[2][1]};
    float4 w2 = {m1[2][2], m1[3][0], m1[3][1], m1[3][2]};
    *(float4*)(base)     = w0;
    *(float4*)(base + 4) = w1;
    *(float4*)(base + 8) = w2;
}

// y2 channels [c0,c0+16) of (pair p, edge el) -> bf16 to LDS, chunk-swizzled:
// logical 16B chunk jc = c0/8 + q stored at slot ((el>>1)+jc)&3.
__device__ __forceinline__ void y2_lds16(int p, int el, int c0, float rv,
                                         const float* __restrict__ wsf,
                                         const float* __restrict__ rb2, char* dst) {
    float y1[MID];
#pragma unroll
    for (int k = 0; k < MID; ++k)
        y1[k] = fmaxf(0.f, wsf[WS_ALPHA1 + p * 32 + k] * rv + wsf[WS_BETA1 + p * 32 + k]);
    unsigned short h[16];
#pragma unroll
    for (int cc = 0; cc < 16; ++cc) {
        int c = c0 + cc;
        float x = rb2[p * 32 + c];
#pragma unroll
        for (int k = 0; k < MID; ++k) x += y1[k] * wsf[WS_W2T + p * 1024 + c * 32 + k];
        h[cc] = f2bf(fmaxf(0.f, wsf[WS_A2 + p * 32 + c] * x + wsf[WS_S2 + p * 32 + c]));
    }
#pragma unroll
    for (int q = 0; q < 2; ++q) {
        int4 pk;
        pk.x = (int)h[q * 8 + 0] | ((int)h[q * 8 + 1] << 16);
        pk.y = (int)h[q * 8 + 2] | ((int)h[q * 8 + 3] << 16);
        pk.z = (int)h[q * 8 + 4] | ((int)h[q * 8 + 5] << 16);
        pk.w = (int)h[q * 8 + 6] | ((int)h[q * 8 + 7] << 16);
        int jc = (c0 >> 3) + q;
        int slot = ((el >> 1) + jc) & 3;
        *(int4*)(dst + el * 64 + slot * 16) = pk;
    }
}

// ---------- K5: MFMA message kernel (r15 structure + swizzled LDS reads) ----------
// block=512 (8 waves), 256 edges/block, grid 256. LDS 64 KB dynamic.
// RULE (r8/r9/r12/r14/r16): keep phase bodies at <=16-MFMA + one output path;
// 512-thr + launch_bounds(512,2) is the only proven 128-VGPR no-spill regime.
__global__ void __launch_bounds__(512, 2) k_msg(const float* __restrict__ r,
        const float* __restrict__ h0, const float* __restrict__ h1,
        const float* __restrict__ b00, const float* __restrict__ b01,
        const float* __restrict__ b10, const float* __restrict__ b11,
        const float* __restrict__ rb2,
        const int* __restrict__ esrc,
        const float* __restrict__ wsf, float* __restrict__ msg) {
    extern __shared__ char smem[];
    short* w3s = (short*)smem;
    const char* wsb = (const char*)wsf;
    int t = threadIdx.x;
    int wv = t >> 6, lane = t & 63;
    int quad = lane >> 4, lq = lane & 15;
    int eb = blockIdx.x << 8;
    // swizzled fragment offsets (col===lq mod 16, el===lq mod 16):
    int woff = (((lq >> 1) + quad) & 3) << 3;     // shorts, for weight images
    int yoff = (((lq >> 1) + quad) & 3) << 4;     // bytes, for y2 tables

    // ================= Phase A: pairs 00 + 10 -> msg0 (RMW) =================
    {
        const float4* src = (const float4*)(wsb + WSB_WA);
        float4* dst = (float4*)smem;
#pragma unroll
        for (int i = 0; i < 4; ++i) dst[i * 512 + t] = src[i * 512 + t];
    }
    {
        int p = __builtin_amdgcn_readfirstlane((t >> 8) * 2);   // 0 or 2
        int el = t & 255;
        float rv = r[eb + el];
        char* dst = smem + 32768 + (t >> 8) * 16384;
        y2_lds16(p, el, 0, rv, wsf, rb2, dst);
        y2_lds16(p, el, 16, rv, wsf, rb2, dst);
    }
    __syncthreads();
#pragma unroll
    for (int g2 = 0; g2 < 2; ++g2) {
        int el = (wv * 2 + g2) * 16 + lq;
        int e = eb + el;
        int s = esrc[e];
        bf16x8 bf0 = *(const bf16x8*)(smem + 32768 + el * 64 + yoff);
        bf16x8 bf2 = *(const bf16x8*)(smem + 49152 + el * 64 + yoff);
        float4 h0q = *(const float4*)(h0 + s * 16 + quad * 4);
        float4 hv0 = *(const float4*)(h1 + s * 48 + quad * 12);
        float4 hv1 = *(const float4*)(h1 + s * 48 + quad * 12 + 4);
        float4 hv2 = *(const float4*)(h1 + s * 48 + quad * 12 + 8);
        float b00v = b00[e];
        float bq0 = b10[e * 3 + 0], bq1 = b10[e * 3 + 1], bq2 = b10[e * 3 + 2];
        float gq0 = bq0 * hv0.x + bq1 * hv0.y + bq2 * hv0.z;
        float gq1 = bq0 * hv0.w + bq1 * hv1.x + bq2 * hv1.y;
        float gq2 = bq0 * hv1.z + bq1 * hv1.w + bq2 * hv2.x;
        float gq3 = bq0 * hv2.y + bq1 * hv2.z + bq2 * hv2.w;
        float4 a0v = *(const float4*)(msg + (size_t)e * 64 + quad * 4);
        float a0[4] = {a0v.x, a0v.y, a0v.z, a0v.w};
#pragma unroll
        for (int m = 0; m < 16; ++m) {
            bf16x8 af = *(const bf16x8*)(w3s + (m * 16 + lq) * 32 + woff);
            f32x4 dd = __builtin_amdgcn_mfma_f32_16x16x32_bf16(af, bf0, (f32x4){0.f,0.f,0.f,0.f}, 0, 0, 0);
            float partial = dd[0] * h0q.x + dd[1] * h0q.y + dd[2] * h0q.z + dd[3] * h0q.w;
            partial += __shfl_xor(partial, 16);
            partial += __shfl_xor(partial, 32);
            a0[m & 3] += (quad == (m >> 2)) ? b00v * partial : 0.f;
        }
#pragma unroll
        for (int m = 0; m < 16; ++m) {
            bf16x8 af = *(const bf16x8*)(w3s + (256 + m * 16 + lq) * 32 + woff);
            f32x4 dd = __builtin_amdgcn_mfma_f32_16x16x32_bf16(af, bf2, (f32x4){0.f,0.f,0.f,0.f}, 0, 0, 0);
            float partial = dd[0] * gq0 + dd[1] * gq1 + dd[2] * gq2 + dd[3] * gq3;
            partial += __shfl_xor(partial, 16);
            partial += __shfl_xor(partial, 32);
            a0[m & 3] += (quad == (m >> 2)) ? partial : 0.f;
        }
        float4 w = {a0[0], a0[1], a0[2], a0[3]};
        *(float4*)(msg + (size_t)e * 64 + quad * 4) = w;
    }
    __syncthreads();

    // ================= Phase B: pair 01 -> msg1 += b01 (x) d01 (RMW) =================
    {
        const float4* src = (const float4*)(wsb + WSB_WB);
        float4* dst = (float4*)smem;
#pragma unroll
        for (int i = 0; i < 2; ++i) dst[i * 512 + t] = src[i * 512 + t];
    }
    {
        int el = t & 255, c0 = (t >> 8) * 16;
        y2_lds16(1, el, c0, r[eb + el], wsf, rb2, smem + 16384);
    }
    __syncthreads();
#pragma unroll
    for (int g2 = 0; g2 < 2; ++g2) {
        int el = (wv * 2 + g2) * 16 + lq;
        int e = eb + el;
        int s = esrc[e];
        bf16x8 bf1 = *(const bf16x8*)(smem + 16384 + el * 64 + yoff);
        float4 h0q = *(const float4*)(h0 + s * 16 + quad * 4);
        float d1[4] = {0.f, 0.f, 0.f, 0.f};
#pragma unroll
        for (int m = 0; m < 16; ++m) {
            bf16x8 af = *(const bf16x8*)(w3s + (m * 16 + lq) * 32 + woff);
            f32x4 dd = __builtin_amdgcn_mfma_f32_16x16x32_bf16(af, bf1, (f32x4){0.f,0.f,0.f,0.f}, 0, 0, 0);
            float partial = dd[0] * h0q.x + dd[1] * h0q.y + dd[2] * h0q.z + dd[3] * h0q.w;
            partial += __shfl_xor(partial, 16);
            partial += __shfl_xor(partial, 32);
            d1[m & 3] += (quad == (m >> 2)) ? partial : 0.f;
        }
        float bo0 = b01[e * 3 + 0], bo1 = b01[e * 3 + 1], bo2 = b01[e * 3 + 2];
        float* base = msg + (size_t)e * 64 + 16 + quad * 12;
        float4 r0 = *(const float4*)(base);
        float4 r1 = *(const float4*)(base + 4);
        float4 r2 = *(const float4*)(base + 8);
        float4 w0 = {r0.x + bo0 * d1[0], r0.y + bo1 * d1[0], r0.z + bo2 * d1[0], r0.w + bo0 * d1[1]};
        float4 w1 = {r1.x + bo1 * d1[1], r1.y + bo2 * d1[1], r1.z + bo0 * d1[2], r1.w + bo1 * d1[2]};
        float4 w2 = {r2.x + bo2 * d1[2], r2.y + bo0 * d1[3], r2.z + bo1 * d1[3], r2.w + bo2 * d1[3]};
        *(float4*)(base)     = w0;
        *(float4*)(base + 4) = w1;
        *(float4*)(base + 8) = w2;
    }
    __syncthreads();

    // ================= Phase C: pair 11 -> msg1 += (RMW) =================
    {
        const float4* src = (const float4*)(wsb + WSB_WC);
        float4* dst = (float4*)smem;
#pragma unroll
        for (int i = 0; i < 6; ++i) dst[i * 512 + t] = src[i * 512 + t];
    }
    {
        int el = t & 255, c0 = (t >> 8) * 16;
        y2_lds16(3, el, c0, r[eb + el], wsf, rb2, smem + 49152);
    }
    __syncthreads();
#pragma unroll
    for (int g2 = 0; g2 < 2; ++g2) {
        int el = (wv * 2 + g2) * 16 + lq;
        int e = eb + el;
        int s = esrc[e];
        bf16x8 bf3 = *(const bf16x8*)(smem + 49152 + el * 64 + yoff);
        float4 hv0 = *(const float4*)(h1 + s * 48 + quad * 12);
        float4 hv1 = *(const float4*)(h1 + s * 48 + quad * 12 + 4);
        float4 hv2 = *(const float4*)(h1 + s * 48 + quad * 12 + 8);
        float h1v[4][3] = {{hv0.x, hv0.y, hv0.z}, {hv0.w, hv1.x, hv1.y},
                           {hv1.z, hv1.w, hv2.x}, {hv2.y, hv2.z, hv2.w}};
        float m1[4][3];
#pragma unroll
        for (int rr = 0; rr < 4; ++rr)
#pragma unroll
            for (int o = 0; o < 3; ++o) m1[rr][o] = 0.f;
#pragma unroll
        for (int f = 0; f < 3; ++f) {
            float Tf[4][3];
#pragma unroll
            for (int o = 0; o < 3; ++o) {
                float bv0 = b11[e * 27 + o * 9 + 0 + f];
                float bv1 = b11[e * 27 + o * 9 + 3 + f];
                float bv2 = b11[e * 27 + o * 9 + 6 + f];
#pragma unroll
                for (int rr = 0; rr < 4; ++rr)
                    Tf[rr][o] = h1v[rr][0] * bv0 + h1v[rr][1] * bv1 + h1v[rr][2] * bv2;
            }
#pragma unroll
            for (int m = 0; m < 16; ++m) {
                int colb = f * 256 + m * 16 + lq;
                bf16x8 af = *(const bf16x8*)(w3s + colb * 32 + woff);
                f32x4 dd = __builtin_amdgcn_mfma_f32_16x16x32_bf16(af, bf3, (f32x4){0.f,0.f,0.f,0.f}, 0, 0, 0);
#pragma unroll
                for (int o = 0; o < 3; ++o) {
                    float po = dd[0] * Tf[0][o] + dd[1] * Tf[1][o] + dd[2] * Tf[2][o] + dd[3] * Tf[3][o];
                    po += __shfl_xor(po, 16);
                    po += __shfl_xor(po, 32);
                    m1[m & 3][o] += (quad == (m >> 2)) ? po : 0.f;
                }
            }
        }
        float* base = msg + (size_t)e * 64 + 16 + quad * 12;
        float4 r0 = *(const float4*)(base);
        float4 r1 = *(const float4*)(base + 4);
        float4 r2 = *(const float4*)(base + 8);
        float4 w0 = {m1[0][0] + r0.x, m1[0][1] + r0.y, m1[0][2] + r0.z, m1[1][0] + r0.w};
        float4 w1 = {m1[1][1] + r1.x, m1[1][2] + r1.y, m1[2][0] + r1.z, m1[2][1] + r1.w};
        float4 w2 = {m1[2][2] + r2.x, m1[3][0] + r2.y, m1[3][1] + r2.z, m1[3][2] + r2.w};
        *(float4*)(base)     = w0;
        *(float4*)(base + 4) = w1;
        *(float4*)(base + 8) = w2;
    }
}

// ---------- K6: gather per node, /cnt, + self-interaction ----------
__global__ void __launch_bounds__(256) k_gather(const float* __restrict__ h0,
        const float* __restrict__ h1, const float* __restrict__ Wself0,
        const float* __restrict__ Wself1, const float* __restrict__ wsf,
        float* __restrict__ out) {
    int wv = threadIdx.x >> 6, lane = threadIdx.x & 63;
    int n = blockIdx.x * 4 + wv;     // grid 1024 blocks
    const int* offs  = ((const int*)wsf) + WS_OFFS_I;
    const int* elist = ((const int*)wsf) + WS_ELIST_I;
    const float* msg = wsf + WS_MSG_F;
    int start = offs[n], end = offs[n + 1];
    int deg = end - start;
    float acc = 0.f;
    for (int j0 = 0; j0 < deg; j0 += 64) {
        int cnt = min(64, deg - j0);
        int eidv = (j0 + lane < deg) ? elist[start + j0 + lane] : 0;
        int jj = 0;
        for (; jj + 3 < cnt; jj += 4) {
            int e0 = __shfl(eidv, jj), e1 = __shfl(eidv, jj + 1);
            int e2 = __shfl(eidv, jj + 2), e3 = __shfl(eidv, jj + 3);
            float v0 = msg[(size_t)e0 * 64 + lane];
            float v1 = msg[(size_t)e1 * 64 + lane];
            float v2 = msg[(size_t)e2 * 64 + lane];
            float v3 = msg[(size_t)e3 * 64 + lane];
            acc += (v0 + v1) + (v2 + v3);
        }
        for (; jj < cnt; ++jj) {
            int eid = __shfl(eidv, jj);
            acc += msg[(size_t)eid * 64 + lane];
        }
    }
    float self = 0.f;
    if (lane < 16) {
        int m = lane;
#pragma unroll
        for (int i = 0; i < 16; ++i) self += Wself0[m * 16 + i] * h0[n * 16 + i];
    } else {
        int idx = lane - 16; int m = idx / 3, o = idx % 3;
#pragma unroll
        for (int i = 0; i < 16; ++i) self += Wself1[m * 16 + i] * h1[n * 48 + i * 3 + o];
    }
    float c = (float)(deg > 0 ? deg : 1);
    float res = acc / c + (deg > 0 ? self : 0.f);
    if (lane < 16) out[n * 16 + lane] = res;
    else           out[65536 + n * 48 + (lane - 16)] = res;
}

extern "C" void kernel_launch(void* const* d_in, const int* in_sizes, int n_in,
                              void* d_out, int out_size, void* d_ws, size_t ws_size,
                              hipStream_t stream) {
    const float* h0   = (const float*)d_in[0];
    const float* h1   = (const float*)d_in[1];
    const float* r    = (const float*)d_in[2];
    const float* b00  = (const float*)d_in[3];
    const float* b01  = (const float*)d_in[4];
    const float* b10  = (const float*)d_in[5];
    const float* b11  = (const float*)d_in[6];
    const float* rw1  = (const float*)d_in[7];
    // d_in[8] = rb1: cancels inside BatchNorm
    const float* rg1  = (const float*)d_in[9];
    const float* rbe1 = (const float*)d_in[10];
    const float* rw2  = (const float*)d_in[11];
    const float* rb2  = (const float*)d_in[12];
    const float* rg2  = (const float*)d_in[13];
    const float* rbe2 = (const float*)d_in[14];
    const float* w300 = (const float*)d_in[15];
    const float* bw300= (const float*)d_in[16];
    const float* w301 = (const float*)d_in[17];
    const float* bw301= (const float*)d_in[18];
    const float* w310 = (const float*)d_in[19];
    const float* bw310= (const float*)d_in[20];
    const float* w311 = (const float*)d_in[21];
    const float* bw311= (const float*)d_in[22];
    const float* Wself0 = (const float*)d_in[23];
    const float* Wself1 = (const float*)d_in[24];
    const int* esrc = (const int*)d_in[25];
    const int* edst = (const int*)d_in[26];
    float* out = (float*)d_out;
    float* wsf = (float*)d_ws;
    float* msg = wsf + WS_MSG_F;

    static bool attr_set = false;
    if (!attr_set) {
        hipFuncSetAttribute((const void*)k_msg,
                            hipFuncAttributeMaxDynamicSharedMemorySize, 65536);
        attr_set = true;
    }

    // single memset: stats + deg + Gram + SUMY (bytes 0..37376)
    hipMemsetAsync(d_ws, 0, 37376, stream);

    k_pre<<<640, 256, 0, stream>>>(rw2, w300, w301, w310, w311,
                                   bw300, bw301, bw310, bw311, r, edst, h0, h1, wsf);
    k_gram<<<128, 512, 0, stream>>>(r, rw1, rg1, rbe1, wsf);
    k_fs<<<1, 1024, 0, stream>>>(rw1, rg1, rbe1, rg2, rbe2, rb2, wsf);
    k_cb<<<1280, 256, 0, stream>>>(edst, b00, b01, b10, b11, esrc, wsf, msg);
    k_msg<<<256, 512, 65536, stream>>>(r, h0, h1, b00, b01, b10, b11, rb2,
                                       esrc, wsf, msg);
    k_gather<<<1024, 256, 0, stream>>>(h0, h1, Wself0, Wself1, wsf, out);
}